// Round 1
// baseline (677.276 us; speedup 1.0000x reference)
//
#include <hip/hip_runtime.h>
#include <cstdint>
#include <cstddef>

#define B_N   16
#define A_N   8732
#define C_N   91
#define FG_N  90
#define K_TOP 400
#define D_N   200
#define NTASK (B_N * FG_N)   // 1440

// ---------------------------------------------------------------------------
// K1: per-anchor softmax (store fg probs transposed (B, 90, A)) + box decode
// ---------------------------------------------------------------------------
__global__ __launch_bounds__(256) void k1_softmax_decode(
    const float* __restrict__ cls, const float* __restrict__ reg,
    const float* __restrict__ anc, float* __restrict__ probs_t,
    float* __restrict__ boxes)
{
#pragma clang fp contract(off)
  int t = blockIdx.x * 256 + threadIdx.x;
  if (t >= B_N * A_N) return;
  int b = t / A_N;
  int a = t - b * A_N;
  const float* lg = cls + (size_t)t * C_N;
  float m = lg[0];
  for (int c = 1; c < C_N; ++c) m = fmaxf(m, lg[c]);
  float s = 0.0f;
  for (int c = 0; c < C_N; ++c) s += expf(lg[c] - m);
  for (int c = 1; c < C_N; ++c)
    probs_t[((size_t)b * FG_N + (c - 1)) * A_N + a] = expf(lg[c] - m) / s;

  float4 rl = *(const float4*)(reg + (size_t)t * 4);
  float4 an = *(const float4*)(anc + (size_t)a * 4);
  float wa = an.z - an.x;
  float ha = an.w - an.y;
  float cxa = an.x + 0.5f * wa;
  float cya = an.y + 0.5f * ha;
  float dx = rl.x / 10.0f;
  float dy = rl.y / 10.0f;
  const float clipv = 4.135166556742356f;   // log(1000/16)
  float dw = fminf(rl.z / 5.0f, clipv);
  float dh = fminf(rl.w / 5.0f, clipv);
  float t1 = dx * wa;  float cx = t1 + cxa;
  float t2 = dy * ha;  float cy = t2 + cya;
  float w = expf(dw) * wa;
  float h = expf(dh) * ha;
  float4 out;
  out.x = fminf(fmaxf(cx - 0.5f * w, 0.0f), 300.0f);
  out.y = fminf(fmaxf(cy - 0.5f * h, 0.0f), 300.0f);
  out.z = fminf(fmaxf(cx + 0.5f * w, 0.0f), 300.0f);
  out.w = fminf(fmaxf(cy + 0.5f * h, 0.0f), 300.0f);
  *(float4*)(boxes + (size_t)t * 4) = out;
}

// ---------------------------------------------------------------------------
// K2: exact top-400 per (image, fg-class) via 3-round radix select on float
//     bits + bitonic sort of candidates with (score desc, anchor asc) order.
// ---------------------------------------------------------------------------
__device__ __forceinline__ void scan_select(int* hist, int nbins, int need,
                                            int tid, int* chunk, int* res)
{
  int per = nbins >> 8;            // 4096 -> 16, 256 -> 1
  int s = 0;
  for (int i = 0; i < per; ++i) s += hist[tid * per + i];
  chunk[tid] = s;
  __syncthreads();
  if (tid == 0) {
    int cum = 0;
    for (int t2 = 255; t2 >= 0; --t2) { int v = chunk[t2]; chunk[t2] = cum; cum += v; }
  }
  __syncthreads();
  int cum = chunk[tid];            // count in strictly-higher chunks
  for (int i = per - 1; i >= 0; --i) {
    int bn = tid * per + i;
    int h = hist[bn];
    if (cum < need && need <= cum + h) { res[0] = bn; res[1] = cum; }
    cum += h;
  }
  __syncthreads();
}

__global__ __launch_bounds__(256) void k2_topk(
    const float* __restrict__ probs_t, int* __restrict__ topk_anchor,
    float* __restrict__ topk_score, int* __restrict__ topk_cnt)
{
  __shared__ int hist[4096];
  __shared__ int chunk[256];
  __shared__ int res[2];
  __shared__ int s_total;
  __shared__ int s_lcnt;
  __shared__ unsigned long long lst[1024];
  const int task = blockIdx.x;
  const int tid = threadIdx.x;
  const float* sc = probs_t + (size_t)task * A_N;

  for (int i = tid; i < 4096; i += 256) hist[i] = 0;
  __syncthreads();
  for (int a = tid; a < A_N; a += 256) {
    float p = sc[a];
    if (p > 0.01f) atomicAdd(&hist[__float_as_uint(p) >> 20], 1);
  }
  __syncthreads();
  { int s = 0;
    for (int i = tid; i < 4096; i += 256) s += hist[i];
    chunk[tid] = s; }
  __syncthreads();
  if (tid == 0) { int tot = 0; for (int i = 0; i < 256; ++i) tot += chunk[i]; s_total = tot; }
  __syncthreads();
  const int total = s_total;
  const int ksel = total < K_TOP ? total : K_TOP;
  unsigned cutoff = 1u;            // all valid keys (positive floats) >= 1
  if (total > K_TOP) {
    int need = K_TOP;
    scan_select(hist, 4096, need, tid, chunk, res);
    const unsigned b1 = (unsigned)res[0];
    need -= res[1];
    __syncthreads();
    for (int i = tid; i < 4096; i += 256) hist[i] = 0;
    __syncthreads();
    for (int a = tid; a < A_N; a += 256) {
      float p = sc[a];
      if (p > 0.01f) {
        unsigned k = __float_as_uint(p);
        if ((k >> 20) == b1) atomicAdd(&hist[(k >> 8) & 0xFFFu], 1);
      }
    }
    __syncthreads();
    scan_select(hist, 4096, need, tid, chunk, res);
    const unsigned b2 = (unsigned)res[0];
    need -= res[1];
    const unsigned pre12 = (b1 << 12) | b2;     // value of (key >> 8)
    __syncthreads();
    hist[tid] = 0;
    __syncthreads();
    for (int a = tid; a < A_N; a += 256) {
      float p = sc[a];
      if (p > 0.01f) {
        unsigned k = __float_as_uint(p);
        if ((k >> 8) == pre12) atomicAdd(&hist[k & 0xFFu], 1);
      }
    }
    __syncthreads();
    scan_select(hist, 256, need, tid, chunk, res);
    cutoff = (pre12 << 8) | (unsigned)res[0];
    __syncthreads();
  }
  if (tid == 0) s_lcnt = 0;
  __syncthreads();
  for (int a = tid; a < A_N; a += 256) {
    float p = sc[a];
    if (p > 0.01f) {
      unsigned k = __float_as_uint(p);
      if (k >= cutoff) {
        int pos = atomicAdd(&s_lcnt, 1);
        if (pos < 1024)
          lst[pos] = ((unsigned long long)k << 32) | (unsigned)(0xFFFFFFFFu - (unsigned)a);
      }
    }
  }
  __syncthreads();
  const int n = s_lcnt < 1024 ? s_lcnt : 1024;
  for (int i = tid; i < 1024; i += 256) if (i >= n) lst[i] = 0ULL;
  __syncthreads();
  // bitonic sort, descending; ties (same score) -> lower anchor first via ~a
  for (int kk = 2; kk <= 1024; kk <<= 1) {
    for (int jj = kk >> 1; jj > 0; jj >>= 1) {
      for (int i = tid; i < 1024; i += 256) {
        int ix = i ^ jj;
        if (ix > i) {
          unsigned long long va = lst[i], vb = lst[ix];
          bool desc = ((i & kk) == 0);
          if (desc ? (va < vb) : (va > vb)) { lst[i] = vb; lst[ix] = va; }
        }
      }
      __syncthreads();
    }
  }
  for (int r = tid; r < K_TOP; r += 256) {
    int anchor = 0;
    float scv = -1.0f;
    if (r < ksel) {
      unsigned long long v = lst[r];
      anchor = (int)(0xFFFFFFFFu - (unsigned)(v & 0xFFFFFFFFull));
      scv = __uint_as_float((unsigned)(v >> 32));
    }
    topk_anchor[(size_t)task * K_TOP + r] = anchor;
    topk_score[(size_t)task * K_TOP + r] = scv;
  }
  if (tid == 0) topk_cnt[task] = ksel;
}

// ---------------------------------------------------------------------------
// K3: per-(image,class) greedy NMS, one wave per class. Kept boxes live in
//     distributed registers (lane k%64 owns slot k/64). IoU computed on
//     OFFSET boxes in exact reference fp32 op order. Cap kept at 200.
// ---------------------------------------------------------------------------
__global__ __launch_bounds__(256) void k3_nms(
    const float* __restrict__ boxes, const int* __restrict__ topk_anchor,
    const float* __restrict__ topk_score, const int* __restrict__ topk_cnt,
    unsigned long long* __restrict__ kept_key, int* __restrict__ kept_cnt)
{
  int gt = blockIdx.x * 256 + threadIdx.x;
  int task = gt >> 6;
  if (task >= NTASK) return;
  int lane = threadIdx.x & 63;
  int b = task / FG_N;
  int c = task - b * FG_N;
  float off = (float)(c + 1) * 302.0f;
  int cnt = topk_cnt[task];
  const int* ta = topk_anchor + (size_t)task * K_TOP;
  const float* ts = topk_score + (size_t)task * K_TOP;
  const float* bx = boxes + (size_t)b * (A_N * 4);
  float kx1[4], ky1[4], kx2[4], ky2[4];
  int nk = 0;
  for (int r = 0; r < cnt; ++r) {
    int anchor = ta[r];
    float x1 = bx[anchor * 4 + 0] + off;
    float y1 = bx[anchor * 4 + 1] + off;
    float x2 = bx[anchor * 4 + 2] + off;
    float y2 = bx[anchor * 4 + 3] + off;
    float area = (x2 - x1) * (y2 - y1);
    bool sup = false;
#pragma unroll
    for (int s = 0; s < 4; ++s) {
      int k = s * 64 + lane;
      if (k < nk) {
        float ix1 = fmaxf(x1, kx1[s]);
        float iy1 = fmaxf(y1, ky1[s]);
        float ix2 = fminf(x2, kx2[s]);
        float iy2 = fminf(y2, ky2[s]);
        float inter = fmaxf(ix2 - ix1, 0.0f) * fmaxf(iy2 - iy1, 0.0f);
        float ka = (kx2[s] - kx1[s]) * (ky2[s] - ky1[s]);
        float iou = inter / (ka + area - inter + 1e-9f);
        if (iou > 0.45f) sup = true;
      }
    }
    if (__ballot(sup) == 0ULL) {
      int slot = nk >> 6;
      if (lane == (nk & 63)) {
        switch (slot) {
          case 0: kx1[0]=x1; ky1[0]=y1; kx2[0]=x2; ky2[0]=y2; break;
          case 1: kx1[1]=x1; ky1[1]=y1; kx2[1]=x2; ky2[1]=y2; break;
          case 2: kx1[2]=x1; ky1[2]=y1; kx2[2]=x2; ky2[2]=y2; break;
          default: kx1[3]=x1; ky1[3]=y1; kx2[3]=x2; ky2[3]=y2; break;
        }
      }
      if (lane == 0) {
        unsigned sb = __float_as_uint(ts[r]);
        kept_key[(size_t)task * D_N + nk] =
            ((unsigned long long)sb << 32) |
            (unsigned)(0xFFFFFFFFu - (unsigned)(c * K_TOP + r));
      }
      ++nk;
      if (nk == D_N) break;
    }
  }
  if (lane == 0) kept_cnt[task] = nk;
}

// ---------------------------------------------------------------------------
// K4: per-image 90-way merge of sorted per-class survivor lists -> global
//     top-200 pick sequence (score desc, flat idx asc == reference argmax).
//     One wave per image; heads prefetched one element ahead.
// ---------------------------------------------------------------------------
__global__ __launch_bounds__(64) void k4_merge(
    const unsigned long long* __restrict__ kept_key,
    const int* __restrict__ kept_cnt, int* __restrict__ pick_flat)
{
  int b = blockIdx.x;
  int lane = threadIdx.x;
  int c0 = lane, c1 = 64 + lane;
  int base0 = b * FG_N + c0;
  int base1 = b * FG_N + c1;
  int cnt0 = (c0 < FG_N) ? kept_cnt[base0] : 0;
  int cnt1 = (c1 < FG_N) ? kept_cnt[base1] : 0;
  const unsigned long long* kk0 = kept_key + (size_t)base0 * D_N;
  const unsigned long long* kk1 = kept_key + (size_t)base1 * D_N;
  int h0 = 0, h1 = 0;
  unsigned long long cur0 = cnt0 > 0 ? kk0[0] : 0ULL;
  unsigned long long nxt0 = cnt0 > 1 ? kk0[1] : 0ULL;
  unsigned long long cur1 = cnt1 > 0 ? kk1[0] : 0ULL;
  unsigned long long nxt1 = cnt1 > 1 ? kk1[1] : 0ULL;
  for (int i = 0; i < D_N; ++i) {
    unsigned long long m = cur0 > cur1 ? cur0 : cur1;
#pragma unroll
    for (int d = 1; d < 64; d <<= 1) {
      unsigned long long o = __shfl_xor(m, d, 64);
      if (o > m) m = o;
    }
    if (m == 0ULL) {
      if (lane == 0) pick_flat[b * D_N + i] = -1;
    } else {
      unsigned flat = 0xFFFFFFFFu - (unsigned)(m & 0xFFFFFFFFull);
      if (lane == 0) pick_flat[b * D_N + i] = (int)flat;
      int cw = (int)(flat / K_TOP);
      if (cw == c0)      { ++h0; cur0 = nxt0; nxt0 = (h0 + 1 < cnt0) ? kk0[h0 + 1] : 0ULL; }
      else if (cw == c1) { ++h1; cur1 = nxt1; nxt1 = (h1 + 1 < cnt1) ? kk1[h1 + 1] : 0ULL; }
    }
  }
}

// ---------------------------------------------------------------------------
// K5: emit boxes / top-2 scores / labels per pick (zeros for invalid picks).
// ---------------------------------------------------------------------------
__global__ __launch_bounds__(256) void k5_output(
    const float* __restrict__ probs_t, const float* __restrict__ boxes,
    const int* __restrict__ topk_anchor, const int* __restrict__ pick_flat,
    float* __restrict__ out)
{
  int t = blockIdx.x * 256 + threadIdx.x;
  if (t >= B_N * D_N) return;
  int b = t / D_N;
  float* ob = out + (size_t)t * 4;
  float* os = out + (size_t)B_N * D_N * 4 + (size_t)t * 2;
  float* ol = out + (size_t)B_N * D_N * 6 + (size_t)t * 2;
  int flat = pick_flat[t];
  if (flat < 0) {
    ob[0] = 0.0f; ob[1] = 0.0f; ob[2] = 0.0f; ob[3] = 0.0f;
    os[0] = 0.0f; os[1] = 0.0f;
    ol[0] = 0.0f; ol[1] = 0.0f;
    return;
  }
  int c = flat / K_TOP;
  int r = flat - c * K_TOP;
  int anchor = topk_anchor[((size_t)b * FG_N + c) * K_TOP + r];
  const float* bp = boxes + ((size_t)b * A_N + anchor) * 4;
  ob[0] = bp[0]; ob[1] = bp[1]; ob[2] = bp[2]; ob[3] = bp[3];
  float v1 = -1.0f; int i1 = 0;
  float v2 = -1.0f; int i2 = 0;
  const float* pp = probs_t + (size_t)b * FG_N * A_N + anchor;
  for (int cc = 0; cc < FG_N; ++cc) {
    float p = pp[(size_t)cc * A_N];
    if (p > v1)      { v2 = v1; i2 = i1; v1 = p; i1 = cc; }
    else if (p > v2) { v2 = p; i2 = cc; }
  }
  os[0] = v1; os[1] = v2;
  ol[0] = (float)(i1 + 1); ol[1] = (float)(i2 + 1);
}

// ---------------------------------------------------------------------------
extern "C" void kernel_launch(void* const* d_in, const int* in_sizes, int n_in,
                              void* d_out, int out_size, void* d_ws, size_t ws_size,
                              hipStream_t stream)
{
  (void)in_sizes; (void)n_in; (void)out_size; (void)ws_size;
  const float* cls = (const float*)d_in[0];
  const float* reg = (const float*)d_in[1];
  const float* anc = (const float*)d_in[2];

  char* w = (char*)d_ws;
  size_t off = 0;
  auto carve = [&](size_t bytes) -> char* {
    char* p = w + off;
    off += (bytes + 255) & ~(size_t)255;
    return p;
  };
  float* probs_t                = (float*)carve((size_t)B_N * FG_N * A_N * 4);
  float* boxes                  = (float*)carve((size_t)B_N * A_N * 4 * 4);
  int* topk_anchor              = (int*)carve((size_t)NTASK * K_TOP * 4);
  float* topk_score             = (float*)carve((size_t)NTASK * K_TOP * 4);
  int* topk_cnt                 = (int*)carve((size_t)NTASK * 4);
  unsigned long long* kept_key  = (unsigned long long*)carve((size_t)NTASK * D_N * 8);
  int* kept_cnt                 = (int*)carve((size_t)NTASK * 4);
  int* pick_flat                = (int*)carve((size_t)B_N * D_N * 4);

  hipLaunchKernelGGL(k1_softmax_decode, dim3((B_N * A_N + 255) / 256), dim3(256), 0, stream,
                     cls, reg, anc, probs_t, boxes);
  hipLaunchKernelGGL(k2_topk, dim3(NTASK), dim3(256), 0, stream,
                     probs_t, topk_anchor, topk_score, topk_cnt);
  hipLaunchKernelGGL(k3_nms, dim3(NTASK / 4), dim3(256), 0, stream,
                     boxes, topk_anchor, topk_score, topk_cnt, kept_key, kept_cnt);
  hipLaunchKernelGGL(k4_merge, dim3(B_N), dim3(64), 0, stream,
                     kept_key, kept_cnt, pick_flat);
  hipLaunchKernelGGL(k5_output, dim3((B_N * D_N + 255) / 256), dim3(256), 0, stream,
                     probs_t, boxes, topk_anchor, pick_flat, (float*)d_out);
}

// Round 2
// 608.493 us; speedup vs baseline: 1.1130x; 1.1130x over previous
//
#include <hip/hip_runtime.h>
#include <cstdint>
#include <cstddef>

#define B_N   16
#define A_N   8732
#define C_N   91
#define FG_N  90
#define K_TOP 400
#define D_N   200
#define NTASK (B_N * FG_N)   // 1440

// ---------------------------------------------------------------------------
// K1: per-anchor softmax (store fg probs transposed (B, 90, A)) + box decode
// ---------------------------------------------------------------------------
__global__ __launch_bounds__(256) void k1_softmax_decode(
    const float* __restrict__ cls, const float* __restrict__ reg,
    const float* __restrict__ anc, float* __restrict__ probs_t,
    float* __restrict__ boxes)
{
#pragma clang fp contract(off)
  int t = blockIdx.x * 256 + threadIdx.x;
  if (t >= B_N * A_N) return;
  int b = t / A_N;
  int a = t - b * A_N;
  const float* lg = cls + (size_t)t * C_N;
  float m = lg[0];
  for (int c = 1; c < C_N; ++c) m = fmaxf(m, lg[c]);
  float s = 0.0f;
  for (int c = 0; c < C_N; ++c) s += expf(lg[c] - m);
  for (int c = 1; c < C_N; ++c)
    probs_t[((size_t)b * FG_N + (c - 1)) * A_N + a] = expf(lg[c] - m) / s;

  float4 rl = *(const float4*)(reg + (size_t)t * 4);
  float4 an = *(const float4*)(anc + (size_t)a * 4);
  float wa = an.z - an.x;
  float ha = an.w - an.y;
  float cxa = an.x + 0.5f * wa;
  float cya = an.y + 0.5f * ha;
  float dx = rl.x / 10.0f;
  float dy = rl.y / 10.0f;
  const float clipv = 4.135166556742356f;   // log(1000/16)
  float dw = fminf(rl.z / 5.0f, clipv);
  float dh = fminf(rl.w / 5.0f, clipv);
  float t1 = dx * wa;  float cx = t1 + cxa;
  float t2 = dy * ha;  float cy = t2 + cya;
  float w = expf(dw) * wa;
  float h = expf(dh) * ha;
  float4 out;
  out.x = fminf(fmaxf(cx - 0.5f * w, 0.0f), 300.0f);
  out.y = fminf(fmaxf(cy - 0.5f * h, 0.0f), 300.0f);
  out.z = fminf(fmaxf(cx + 0.5f * w, 0.0f), 300.0f);
  out.w = fminf(fmaxf(cy + 0.5f * h, 0.0f), 300.0f);
  *(float4*)(boxes + (size_t)t * 4) = out;
}

// ---------------------------------------------------------------------------
// K2: exact top-400 per (image, fg-class) via 3-round radix select on float
//     bits + bitonic sort of candidates with (score desc, anchor asc) order.
// ---------------------------------------------------------------------------
__device__ __forceinline__ void scan_select(int* hist, int nbins, int need,
                                            int tid, int* chunk, int* res)
{
  int per = nbins >> 8;            // 4096 -> 16, 256 -> 1
  int s = 0;
  for (int i = 0; i < per; ++i) s += hist[tid * per + i];
  chunk[tid] = s;
  __syncthreads();
  if (tid == 0) {
    int cum = 0;
    for (int t2 = 255; t2 >= 0; --t2) { int v = chunk[t2]; chunk[t2] = cum; cum += v; }
  }
  __syncthreads();
  int cum = chunk[tid];            // count in strictly-higher chunks
  for (int i = per - 1; i >= 0; --i) {
    int bn = tid * per + i;
    int h = hist[bn];
    if (cum < need && need <= cum + h) { res[0] = bn; res[1] = cum; }
    cum += h;
  }
  __syncthreads();
}

__global__ __launch_bounds__(256) void k2_topk(
    const float* __restrict__ probs_t, int* __restrict__ topk_anchor,
    float* __restrict__ topk_score, int* __restrict__ topk_cnt)
{
  __shared__ int hist[4096];
  __shared__ int chunk[256];
  __shared__ int res[2];
  __shared__ int s_total;
  __shared__ int s_lcnt;
  __shared__ unsigned long long lst[1024];
  const int task = blockIdx.x;
  const int tid = threadIdx.x;
  const float* sc = probs_t + (size_t)task * A_N;

  for (int i = tid; i < 4096; i += 256) hist[i] = 0;
  __syncthreads();
  for (int a = tid; a < A_N; a += 256) {
    float p = sc[a];
    if (p > 0.01f) atomicAdd(&hist[__float_as_uint(p) >> 20], 1);
  }
  __syncthreads();
  { int s = 0;
    for (int i = tid; i < 4096; i += 256) s += hist[i];
    chunk[tid] = s; }
  __syncthreads();
  if (tid == 0) { int tot = 0; for (int i = 0; i < 256; ++i) tot += chunk[i]; s_total = tot; }
  __syncthreads();
  const int total = s_total;
  const int ksel = total < K_TOP ? total : K_TOP;
  unsigned cutoff = 1u;            // all valid keys (positive floats) >= 1
  if (total > K_TOP) {
    int need = K_TOP;
    scan_select(hist, 4096, need, tid, chunk, res);
    const unsigned b1 = (unsigned)res[0];
    need -= res[1];
    __syncthreads();
    for (int i = tid; i < 4096; i += 256) hist[i] = 0;
    __syncthreads();
    for (int a = tid; a < A_N; a += 256) {
      float p = sc[a];
      if (p > 0.01f) {
        unsigned k = __float_as_uint(p);
        if ((k >> 20) == b1) atomicAdd(&hist[(k >> 8) & 0xFFFu], 1);
      }
    }
    __syncthreads();
    scan_select(hist, 4096, need, tid, chunk, res);
    const unsigned b2 = (unsigned)res[0];
    need -= res[1];
    const unsigned pre12 = (b1 << 12) | b2;     // value of (key >> 8)
    __syncthreads();
    hist[tid] = 0;
    __syncthreads();
    for (int a = tid; a < A_N; a += 256) {
      float p = sc[a];
      if (p > 0.01f) {
        unsigned k = __float_as_uint(p);
        if ((k >> 8) == pre12) atomicAdd(&hist[k & 0xFFu], 1);
      }
    }
    __syncthreads();
    scan_select(hist, 256, need, tid, chunk, res);
    cutoff = (pre12 << 8) | (unsigned)res[0];
    __syncthreads();
  }
  if (tid == 0) s_lcnt = 0;
  __syncthreads();
  for (int a = tid; a < A_N; a += 256) {
    float p = sc[a];
    if (p > 0.01f) {
      unsigned k = __float_as_uint(p);
      if (k >= cutoff) {
        int pos = atomicAdd(&s_lcnt, 1);
        if (pos < 1024)
          lst[pos] = ((unsigned long long)k << 32) | (unsigned)(0xFFFFFFFFu - (unsigned)a);
      }
    }
  }
  __syncthreads();
  const int n = s_lcnt < 1024 ? s_lcnt : 1024;
  for (int i = tid; i < 1024; i += 256) if (i >= n) lst[i] = 0ULL;
  __syncthreads();
  // bitonic sort, descending; ties (same score) -> lower anchor first via ~a
  for (int kk = 2; kk <= 1024; kk <<= 1) {
    for (int jj = kk >> 1; jj > 0; jj >>= 1) {
      for (int i = tid; i < 1024; i += 256) {
        int ix = i ^ jj;
        if (ix > i) {
          unsigned long long va = lst[i], vb = lst[ix];
          bool desc = ((i & kk) == 0);
          if (desc ? (va < vb) : (va > vb)) { lst[i] = vb; lst[ix] = va; }
        }
      }
      __syncthreads();
    }
  }
  for (int r = tid; r < K_TOP; r += 256) {
    int anchor = 0;
    float scv = -1.0f;
    if (r < ksel) {
      unsigned long long v = lst[r];
      anchor = (int)(0xFFFFFFFFu - (unsigned)(v & 0xFFFFFFFFull));
      scv = __uint_as_float((unsigned)(v >> 32));
    }
    topk_anchor[(size_t)task * K_TOP + r] = anchor;
    topk_score[(size_t)task * K_TOP + r] = scv;
  }
  if (tid == 0) topk_cnt[task] = ksel;
}

// ---------------------------------------------------------------------------
// K3: per-(image,class) greedy NMS, one wave per class.
//     Candidates staged into LDS (offset pre-applied) in one coalesced pass;
//     greedy loop runs from LDS with software-pipelined next-candidate
//     prefetch. Kept boxes + areas in distributed registers (lane k%64 owns
//     slot k/64); kept_key written in a parallel epilogue, not in the loop.
//     IoU in exact reference fp32 op order (contract off). Cap kept at 200.
// ---------------------------------------------------------------------------
__global__ __launch_bounds__(256) void k3_nms(
    const float* __restrict__ boxes, const int* __restrict__ topk_anchor,
    const float* __restrict__ topk_score, const int* __restrict__ topk_cnt,
    unsigned long long* __restrict__ kept_key, int* __restrict__ kept_cnt)
{
#pragma clang fp contract(off)
  __shared__ float4 cbox[4][K_TOP];      // 25.6 KB
  const int wid  = threadIdx.x >> 6;
  const int lane = threadIdx.x & 63;
  const int task = blockIdx.x * 4 + wid; // grid is exactly NTASK/4
  const int b = task / FG_N;
  const int c = task - b * FG_N;
  const float off = (float)(c + 1) * 302.0f;
  const int cnt = topk_cnt[task];
  const int* ta = topk_anchor + (size_t)task * K_TOP;
  const float* ts = topk_score + (size_t)task * K_TOP;
  const float* bx = boxes + (size_t)b * (A_N * 4);

  for (int k = lane; k < cnt; k += 64) {
    int anchor = ta[k];
    float4 v = *(const float4*)(bx + (size_t)anchor * 4);
    v.x += off; v.y += off; v.z += off; v.w += off;
    cbox[wid][k] = v;
  }
  __syncthreads();

  float kx1[4], ky1[4], kx2[4], ky2[4], kar[4];
  int   kr[4];
  int nk = 0;
  if (cnt > 0) {
    float4 cur = cbox[wid][0];
    for (int r = 0; r < cnt; ++r) {
      int rn = (r + 1 < cnt) ? r + 1 : r;
      float4 nxt = cbox[wid][rn];          // prefetch, independent of append
      float area = (cur.z - cur.x) * (cur.w - cur.y);
      bool sup = false;
#pragma unroll
      for (int s = 0; s < 4; ++s) {
        int k = s * 64 + lane;
        if (k < nk) {
          float ix1 = fmaxf(cur.x, kx1[s]);
          float iy1 = fmaxf(cur.y, ky1[s]);
          float ix2 = fminf(cur.z, kx2[s]);
          float iy2 = fminf(cur.w, ky2[s]);
          float inter = fmaxf(ix2 - ix1, 0.0f) * fmaxf(iy2 - iy1, 0.0f);
          float iou = inter / (kar[s] + area - inter + 1e-9f);
          sup = sup || (iou > 0.45f);
        }
      }
      if (__ballot(sup) == 0ULL) {
        if (lane == (nk & 63)) {
          switch (nk >> 6) {
            case 0: kx1[0]=cur.x; ky1[0]=cur.y; kx2[0]=cur.z; ky2[0]=cur.w; kar[0]=area; kr[0]=r; break;
            case 1: kx1[1]=cur.x; ky1[1]=cur.y; kx2[1]=cur.z; ky2[1]=cur.w; kar[1]=area; kr[1]=r; break;
            case 2: kx1[2]=cur.x; ky1[2]=cur.y; kx2[2]=cur.z; ky2[2]=cur.w; kar[2]=area; kr[2]=r; break;
            default: kx1[3]=cur.x; ky1[3]=cur.y; kx2[3]=cur.z; ky2[3]=cur.w; kar[3]=area; kr[3]=r; break;
          }
        }
        ++nk;
        if (nk == D_N) break;
      }
      cur = nxt;
    }
  }
#pragma unroll
  for (int s = 0; s < 4; ++s) {
    int k = s * 64 + lane;
    if (k < nk) {
      int r = kr[s];
      unsigned sb = __float_as_uint(ts[r]);
      kept_key[(size_t)task * D_N + k] =
          ((unsigned long long)sb << 32) |
          (unsigned)(0xFFFFFFFFu - (unsigned)(c * K_TOP + r));
    }
  }
  if (lane == 0) kept_cnt[task] = nk;
}

// ---------------------------------------------------------------------------
// K4: per-image 90-way merge of sorted per-class survivor lists -> global
//     top-200 pick sequence (score desc, flat idx asc == reference argmax).
//     One wave per image; heads prefetched one element ahead.
// ---------------------------------------------------------------------------
__global__ __launch_bounds__(64) void k4_merge(
    const unsigned long long* __restrict__ kept_key,
    const int* __restrict__ kept_cnt, int* __restrict__ pick_flat)
{
  int b = blockIdx.x;
  int lane = threadIdx.x;
  int c0 = lane, c1 = 64 + lane;
  int base0 = b * FG_N + c0;
  int base1 = b * FG_N + c1;
  int cnt0 = (c0 < FG_N) ? kept_cnt[base0] : 0;
  int cnt1 = (c1 < FG_N) ? kept_cnt[base1] : 0;
  const unsigned long long* kk0 = kept_key + (size_t)base0 * D_N;
  const unsigned long long* kk1 = kept_key + (size_t)base1 * D_N;
  int h0 = 0, h1 = 0;
  unsigned long long cur0 = cnt0 > 0 ? kk0[0] : 0ULL;
  unsigned long long nxt0 = cnt0 > 1 ? kk0[1] : 0ULL;
  unsigned long long cur1 = cnt1 > 0 ? kk1[0] : 0ULL;
  unsigned long long nxt1 = cnt1 > 1 ? kk1[1] : 0ULL;
  for (int i = 0; i < D_N; ++i) {
    unsigned long long m = cur0 > cur1 ? cur0 : cur1;
#pragma unroll
    for (int d = 1; d < 64; d <<= 1) {
      unsigned long long o = __shfl_xor(m, d, 64);
      if (o > m) m = o;
    }
    if (m == 0ULL) {
      if (lane == 0) pick_flat[b * D_N + i] = -1;
    } else {
      unsigned flat = 0xFFFFFFFFu - (unsigned)(m & 0xFFFFFFFFull);
      if (lane == 0) pick_flat[b * D_N + i] = (int)flat;
      int cw = (int)(flat / K_TOP);
      if (cw == c0)      { ++h0; cur0 = nxt0; nxt0 = (h0 + 1 < cnt0) ? kk0[h0 + 1] : 0ULL; }
      else if (cw == c1) { ++h1; cur1 = nxt1; nxt1 = (h1 + 1 < cnt1) ? kk1[h1 + 1] : 0ULL; }
    }
  }
}

// ---------------------------------------------------------------------------
// K5: emit boxes / top-2 scores / labels per pick (zeros for invalid picks).
// ---------------------------------------------------------------------------
__global__ __launch_bounds__(256) void k5_output(
    const float* __restrict__ probs_t, const float* __restrict__ boxes,
    const int* __restrict__ topk_anchor, const int* __restrict__ pick_flat,
    float* __restrict__ out)
{
  int t = blockIdx.x * 256 + threadIdx.x;
  if (t >= B_N * D_N) return;
  int b = t / D_N;
  float* ob = out + (size_t)t * 4;
  float* os = out + (size_t)B_N * D_N * 4 + (size_t)t * 2;
  float* ol = out + (size_t)B_N * D_N * 6 + (size_t)t * 2;
  int flat = pick_flat[t];
  if (flat < 0) {
    ob[0] = 0.0f; ob[1] = 0.0f; ob[2] = 0.0f; ob[3] = 0.0f;
    os[0] = 0.0f; os[1] = 0.0f;
    ol[0] = 0.0f; ol[1] = 0.0f;
    return;
  }
  int c = flat / K_TOP;
  int r = flat - c * K_TOP;
  int anchor = topk_anchor[((size_t)b * FG_N + c) * K_TOP + r];
  const float* bp = boxes + ((size_t)b * A_N + anchor) * 4;
  ob[0] = bp[0]; ob[1] = bp[1]; ob[2] = bp[2]; ob[3] = bp[3];
  float v1 = -1.0f; int i1 = 0;
  float v2 = -1.0f; int i2 = 0;
  const float* pp = probs_t + (size_t)b * FG_N * A_N + anchor;
  for (int cc = 0; cc < FG_N; ++cc) {
    float p = pp[(size_t)cc * A_N];
    if (p > v1)      { v2 = v1; i2 = i1; v1 = p; i1 = cc; }
    else if (p > v2) { v2 = p; i2 = cc; }
  }
  os[0] = v1; os[1] = v2;
  ol[0] = (float)(i1 + 1); ol[1] = (float)(i2 + 1);
}

// ---------------------------------------------------------------------------
extern "C" void kernel_launch(void* const* d_in, const int* in_sizes, int n_in,
                              void* d_out, int out_size, void* d_ws, size_t ws_size,
                              hipStream_t stream)
{
  (void)in_sizes; (void)n_in; (void)out_size; (void)ws_size;
  const float* cls = (const float*)d_in[0];
  const float* reg = (const float*)d_in[1];
  const float* anc = (const float*)d_in[2];

  char* w = (char*)d_ws;
  size_t off = 0;
  auto carve = [&](size_t bytes) -> char* {
    char* p = w + off;
    off += (bytes + 255) & ~(size_t)255;
    return p;
  };
  float* probs_t                = (float*)carve((size_t)B_N * FG_N * A_N * 4);
  float* boxes                  = (float*)carve((size_t)B_N * A_N * 4 * 4);
  int* topk_anchor              = (int*)carve((size_t)NTASK * K_TOP * 4);
  float* topk_score             = (float*)carve((size_t)NTASK * K_TOP * 4);
  int* topk_cnt                 = (int*)carve((size_t)NTASK * 4);
  unsigned long long* kept_key  = (unsigned long long*)carve((size_t)NTASK * D_N * 8);
  int* kept_cnt                 = (int*)carve((size_t)NTASK * 4);
  int* pick_flat                = (int*)carve((size_t)B_N * D_N * 4);

  hipLaunchKernelGGL(k1_softmax_decode, dim3((B_N * A_N + 255) / 256), dim3(256), 0, stream,
                     cls, reg, anc, probs_t, boxes);
  hipLaunchKernelGGL(k2_topk, dim3(NTASK), dim3(256), 0, stream,
                     probs_t, topk_anchor, topk_score, topk_cnt);
  hipLaunchKernelGGL(k3_nms, dim3(NTASK / 4), dim3(256), 0, stream,
                     boxes, topk_anchor, topk_score, topk_cnt, kept_key, kept_cnt);
  hipLaunchKernelGGL(k4_merge, dim3(B_N), dim3(64), 0, stream,
                     kept_key, kept_cnt, pick_flat);
  hipLaunchKernelGGL(k5_output, dim3((B_N * D_N + 255) / 256), dim3(256), 0, stream,
                     probs_t, boxes, topk_anchor, pick_flat, (float*)d_out);
}